// Round 10
// baseline (51.151 us; speedup 1.0000x reference)
//
#include <hip/hip_runtime.h>
#include <hip/hip_bf16.h>

// HopfieldEnergy: energy_i = -(logsumexp_j(2 * xn_i . an_j) - log M)/2 + 1.0
// M = N = 8192, K = 256. bf16-MFMA matmul + fused row exp-sum.
// R3-R9: every graft onto the 2-phase (syncthreads-per-step) skeleton was
// null -- matching m233's "2-phase stall" (barrier vmcnt(0) drain is ~72%
// overhead; removing single pieces doesn't help). R10 = T3/T4: 4 LDS
// buffers, counted vmcnt (never 0 in loop), RAW s_barrier (no drain),
// stage issued 3 tiles ahead; T5 setprio on the MFMA cluster.

#define MROWS 8192
#define NROWS 8192
#define KDIM  256
#define BM    256
#define BN    32
#define NSPLIT 16

// 2*log2(e): xb holds (2*log2e)*x_n so exp(2*s) == exp2(acc) directly.
#define XSCALE 2.8853900817779268f

typedef __bf16 bf16x8 __attribute__((ext_vector_type(8)));
typedef float  f32x4  __attribute__((ext_vector_type(4)));

static __device__ __forceinline__ unsigned short f2bf(float f) {
    __hip_bfloat16 h = __float2bfloat16(f);
    union { __hip_bfloat16 h; unsigned short u; } c;
    c.h = h;
    return c.u;
}

// One wave per row. Rows [0,8192) = x, [8192,16384) = a.
// xb = (2*log2e)*x_n, linear. ab = a_n with each row's 16B chunks XOR-swizzled
// by ((j&7)<<4) so expsum can global_load_lds linearly and ds_read swizzled.
__global__ void normalize_kernel(const float* __restrict__ x,
                                 const float* __restrict__ a,
                                 __hip_bfloat16* __restrict__ xb,
                                 __hip_bfloat16* __restrict__ ab) {
    const int lane = threadIdx.x & 63;
    const int gwave = (blockIdx.x * blockDim.x + threadIdx.x) >> 6;
    const bool is_x = gwave < MROWS;
    const int r = is_x ? gwave : gwave - MROWS;
    const float* src = (is_x ? x : a) + (size_t)r * KDIM;

    float4 v = reinterpret_cast<const float4*>(src)[lane];
    float ss = v.x * v.x + v.y * v.y + v.z * v.z + v.w * v.w;
    #pragma unroll
    for (int o = 32; o > 0; o >>= 1) ss += __shfl_xor(ss, o);

    const float inv = 1.0f / fmaxf(sqrtf(ss), 1e-12f);
    const float scale = is_x ? (XSCALE * inv) : inv;

    union { ushort4 u4; unsigned short us[4]; } pk;
    pk.us[0] = f2bf(v.x * scale);
    pk.us[1] = f2bf(v.y * scale);
    pk.us[2] = f2bf(v.z * scale);
    pk.us[3] = f2bf(v.w * scale);

    if (is_x) {
        reinterpret_cast<ushort4*>(xb + (size_t)r * KDIM)[lane] = pk.u4;
    } else {
        char* base = (char*)(ab + (size_t)r * KDIM);
        const int off = (lane * 8) ^ ((r & 7) << 4);  // pre-swizzle source side
        *reinterpret_cast<ushort4*>(base + off) = pk.u4;
    }
}

// grid (MROWS/BM=32, NSPLIT=16) = 512 blocks, 512 threads (8 waves).
// Wave owns 32 rows (f=2, afrag 64 VGPR), cap 128 via launch_bounds(512,4)
// -> 2 blocks/CU = 4 waves/SIMD. LDS: 4 buffers x 16KB = 64KB -> 2 blocks.
// Pipeline: prologue stages tiles 0..2 (2 gload_lds/tile/wave = 6 in
// flight); per step: vmcnt(4) [own tile landed] -> raw s_barrier (NO
// vmcnt(0) drain) -> stage t+3 -> setprio MFMA cluster -> exp drain.
__global__ __launch_bounds__(512, 4) void expsum_kernel(
    const __hip_bfloat16* __restrict__ xb,
    const __hip_bfloat16* __restrict__ ab,
    float* __restrict__ partial) {
    __shared__ __attribute__((aligned(16))) char lds[4][BN * 512];  // 64 KB

    const int tid = threadIdx.x;
    const int lane = tid & 63;
    const int w = tid >> 6;          // 0..7
    const int mbase = blockIdx.x * BM;
    const int jstart = blockIdx.y * (NROWS / NSPLIT);
    // nsteps = 512 / BN = 16 (fixed)

    // A fragments: lane holds row (lane&15), k chunk (lane>>4)*8 (+ks*32).
    bf16x8 afrag[2][8];
    const int arow = mbase + w * 32 + (lane & 15);
    const int kb = (lane >> 4) * 8;
    #pragma unroll
    for (int f = 0; f < 2; ++f)
        #pragma unroll
        for (int ks = 0; ks < 8; ++ks)
            afrag[f][ks] = *reinterpret_cast<const bf16x8*>(
                xb + (size_t)(arow + f * 16) * KDIM + ks * 32 + kb);

    auto stage = [&](int buf, int j0) {
        const char* src = (const char*)ab + (size_t)j0 * 512;
        #pragma unroll
        for (int i = 0; i < 2; ++i) {
            const int chunk = w * 2 + i;  // 16 chunks x 1 KB = 16 KB tile
            __builtin_amdgcn_global_load_lds(
                (const __attribute__((address_space(1))) void*)
                    (src + chunk * 1024 + lane * 16),
                (__attribute__((address_space(3))) void*)
                    (&lds[buf][chunk * 1024]),
                16, 0, 0);
        }
    };

    float rowsum[2][4] = {{0.f, 0.f, 0.f, 0.f}, {0.f, 0.f, 0.f, 0.f}};
    const int cb = (lane >> 4) * 16;  // byte col base within a k-group
    const int rl = lane & 15;
    const int r0 = rl;
    const int r1 = rl + 16;

    stage(0, jstart);
    stage(1, jstart + BN);
    stage(2, jstart + 2 * BN);

    // One pipeline step. VMSTR: literal vmcnt immediate (counted, not 0 in
    // the main loop). Raw s_barrier: NO implicit vmcnt/lgkm drain.
#define KSTEP(T, VMSTR, DOSTAGE)                                              \
    {                                                                         \
        asm volatile("s_waitcnt " VMSTR ::: "memory");                        \
        __builtin_amdgcn_sched_barrier(0);                                    \
        __builtin_amdgcn_s_barrier();                                         \
        __builtin_amdgcn_sched_barrier(0);                                    \
        if (DOSTAGE) stage(((T) + 3) & 3, jstart + ((T) + 3) * BN);           \
        const char* L = lds[(T) & 3];                                         \
        f32x4 acc[2][2];                                                      \
        _Pragma("unroll")                                                     \
        for (int f = 0; f < 2; ++f) {                                         \
            acc[f][0] = (f32x4){0.f, 0.f, 0.f, 0.f};                          \
            acc[f][1] = (f32x4){0.f, 0.f, 0.f, 0.f};                          \
        }                                                                     \
        __builtin_amdgcn_s_setprio(1);                                        \
        _Pragma("unroll")                                                     \
        for (int ks = 0; ks < 8; ++ks) {                                      \
            const int bcol = ks * 64 + cb;                                    \
            bf16x8 b0 = *reinterpret_cast<const bf16x8*>(                     \
                &L[r0 * 512 + (bcol ^ ((r0 & 7) << 4))]);                     \
            bf16x8 b1 = *reinterpret_cast<const bf16x8*>(                     \
                &L[r1 * 512 + (bcol ^ ((r1 & 7) << 4))]);                     \
            _Pragma("unroll")                                                 \
            for (int f = 0; f < 2; ++f) {                                     \
                acc[f][0] = __builtin_amdgcn_mfma_f32_16x16x32_bf16(          \
                    afrag[f][ks], b0, acc[f][0], 0, 0, 0);                    \
                acc[f][1] = __builtin_amdgcn_mfma_f32_16x16x32_bf16(          \
                    afrag[f][ks], b1, acc[f][1], 0, 0, 0);                    \
            }                                                                 \
        }                                                                     \
        __builtin_amdgcn_s_setprio(0);                                        \
        _Pragma("unroll")                                                     \
        for (int f = 0; f < 2; ++f)                                           \
            _Pragma("unroll")                                                 \
            for (int g = 0; g < 2; ++g)                                       \
                _Pragma("unroll")                                             \
                for (int r = 0; r < 4; ++r)                                   \
                    rowsum[f][r] += __builtin_amdgcn_exp2f(acc[f][g][r]);     \
    }

    // Main: tiles 0..13 wait vmcnt(4) (2 newer tiles x 2 loads in flight);
    // stage t+3 while t+1, t+2 fly. Epilogue peels the drain.
    for (int t = 0; t < 14; ++t) {
        KSTEP(t, "vmcnt(4)", (t < 13))
    }
    KSTEP(14, "vmcnt(2)", false)
    KSTEP(15, "vmcnt(0)", false)
#undef KSTEP

    // sum across the 16 lanes sharing (lane>>4)
    #pragma unroll
    for (int f = 0; f < 2; ++f)
        #pragma unroll
        for (int r = 0; r < 4; ++r) {
            float s = rowsum[f][r];
            s += __shfl_xor(s, 1);
            s += __shfl_xor(s, 2);
            s += __shfl_xor(s, 4);
            s += __shfl_xor(s, 8);
            rowsum[f][r] = s;
        }

    if ((lane & 15) == 0) {
        const int rbase = mbase + w * 32 + (lane >> 4) * 4;
        #pragma unroll
        for (int f = 0; f < 2; ++f)
            #pragma unroll
            for (int r = 0; r < 4; ++r)
                partial[(size_t)blockIdx.y * MROWS + rbase + f * 16 + r] = rowsum[f][r];
    }
}

__global__ void finalize_kernel(const float* __restrict__ partial,
                                float* __restrict__ out) {
    const int i = blockIdx.x * blockDim.x + threadIdx.x;
    float s = 0.f;
    #pragma unroll
    for (int p = 0; p < NSPLIT; ++p) s += partial[(size_t)p * MROWS + i];
    // energy = -(log(sum)-log M)/2 + 0.5||xn||^2 + 0.5 max||an||^2, norms == 1
    out[i] = -0.5f * (logf(s) - logf((float)NROWS)) + 1.0f;
}

extern "C" void kernel_launch(void* const* d_in, const int* in_sizes, int n_in,
                              void* d_out, int out_size, void* d_ws, size_t ws_size,
                              hipStream_t stream) {
    const float* x = (const float*)d_in[0];
    const float* a = (const float*)d_in[1];
    float* out = (float*)d_out;

    char* ws = (char*)d_ws;
    size_t off = 0;
    __hip_bfloat16* xb = (__hip_bfloat16*)(ws + off); off += (size_t)MROWS * KDIM * 2;  // 4 MiB
    __hip_bfloat16* ab = (__hip_bfloat16*)(ws + off); off += (size_t)NROWS * KDIM * 2;  // 4 MiB
    float* partial     = (float*)(ws + off);          // NSPLIT*MROWS*4 = 512 KiB

    normalize_kernel<<<(2 * MROWS) / 4, 256, 0, stream>>>(x, a, xb, ab);
    expsum_kernel<<<dim3(MROWS / BM, NSPLIT), 512, 0, stream>>>(xb, ab, partial);
    finalize_kernel<<<MROWS / 256, 256, 0, stream>>>(partial, out);
}

// Round 11
// 48.326 us; speedup vs baseline: 1.0585x; 1.0585x over previous
//
#include <hip/hip_runtime.h>
#include <hip/hip_bf16.h>

// HopfieldEnergy: energy_i = -(logsumexp_j(2 * xn_i . an_j) - log M)/2 + 1.0
// M = N = 8192, K = 256. bf16-MFMA matmul + fused row exp-sum.
// R10 profile caught expsum: VGPR_Count=64 with ~110 live (afrag 64 + acc 16
// + temps) and 27 MB of scratch spill WRITES per dispatch. Register
// starvation from launch_bounds min-waves explains the ~50% MfmaUtil wall
// and every null graft (R4-R10). R11 = R9 exactly, with launch_bounds
// (512,4) -> (512,2): allocator target 2 waves/EU, cap 256 -> afrag resident.

#define MROWS 8192
#define NROWS 8192
#define KDIM  256
#define BM    256
#define BN    64
#define NSPLIT 16

// 2*log2(e): xb holds (2*log2e)*x_n so exp(2*s) == exp2(acc) directly.
#define XSCALE 2.8853900817779268f

typedef __bf16 bf16x8 __attribute__((ext_vector_type(8)));
typedef float  f32x4  __attribute__((ext_vector_type(4)));

static __device__ __forceinline__ unsigned short f2bf(float f) {
    __hip_bfloat16 h = __float2bfloat16(f);
    union { __hip_bfloat16 h; unsigned short u; } c;
    c.h = h;
    return c.u;
}

// One wave per row. Rows [0,8192) = x, [8192,16384) = a.
// xb = (2*log2e)*x_n, linear. ab = a_n with each row's 16B chunks XOR-swizzled
// by ((j&7)<<4) so expsum can global_load_lds linearly and ds_read swizzled.
__global__ void normalize_kernel(const float* __restrict__ x,
                                 const float* __restrict__ a,
                                 __hip_bfloat16* __restrict__ xb,
                                 __hip_bfloat16* __restrict__ ab) {
    const int lane = threadIdx.x & 63;
    const int gwave = (blockIdx.x * blockDim.x + threadIdx.x) >> 6;
    const bool is_x = gwave < MROWS;
    const int r = is_x ? gwave : gwave - MROWS;
    const float* src = (is_x ? x : a) + (size_t)r * KDIM;

    float4 v = reinterpret_cast<const float4*>(src)[lane];
    float ss = v.x * v.x + v.y * v.y + v.z * v.z + v.w * v.w;
    #pragma unroll
    for (int o = 32; o > 0; o >>= 1) ss += __shfl_xor(ss, o);

    const float inv = 1.0f / fmaxf(sqrtf(ss), 1e-12f);
    const float scale = is_x ? (XSCALE * inv) : inv;

    union { ushort4 u4; unsigned short us[4]; } pk;
    pk.us[0] = f2bf(v.x * scale);
    pk.us[1] = f2bf(v.y * scale);
    pk.us[2] = f2bf(v.z * scale);
    pk.us[3] = f2bf(v.w * scale);

    if (is_x) {
        reinterpret_cast<ushort4*>(xb + (size_t)r * KDIM)[lane] = pk.u4;
    } else {
        char* base = (char*)(ab + (size_t)r * KDIM);
        const int off = (lane * 8) ^ ((r & 7) << 4);  // pre-swizzle source side
        *reinterpret_cast<ushort4*>(base + off) = pk.u4;
    }
}

// grid (MROWS/BM=32, NSPLIT=16) = 512 blocks, 512 threads (8 waves).
// Wave owns 32 rows (f=2, afrag 64 VGPR, ~115 live total).
// __launch_bounds__(512,2): allocator target 2 waves/EU (cap 256 VGPR) so
// afrag is register-resident -- R10 showed (512,4) starves to 64 VGPR and
// spills ~27MB/dispatch. HW occupancy: LDS 64KB/block -> 2 blocks/CU.
// B tile (BN=64 a-rows, 32KB) double-buffered in LDS via global_load_lds
// (source pre-swizzled, LDS linear), swizzled conflict-free ds_read_b128.
__global__ __launch_bounds__(512, 2) void expsum_kernel(
    const __hip_bfloat16* __restrict__ xb,
    const __hip_bfloat16* __restrict__ ab,
    float* __restrict__ partial) {
    __shared__ __attribute__((aligned(16))) char lds[2][BN * 512];

    const int tid = threadIdx.x;
    const int lane = tid & 63;
    const int w = tid >> 6;          // 0..7
    const int mbase = blockIdx.x * BM;
    const int jstart = blockIdx.y * (NROWS / NSPLIT);
    const int nsteps = (NROWS / NSPLIT) / BN;  // 8

    // A fragments: lane holds row (lane&15), k chunk (lane>>4)*8 (+ks*32).
    bf16x8 afrag[2][8];
    const int arow = mbase + w * 32 + (lane & 15);
    const int kb = (lane >> 4) * 8;
    #pragma unroll
    for (int f = 0; f < 2; ++f)
        #pragma unroll
        for (int ks = 0; ks < 8; ++ks)
            afrag[f][ks] = *reinterpret_cast<const bf16x8*>(
                xb + (size_t)(arow + f * 16) * KDIM + ks * 32 + kb);

    auto stage = [&](int buf, int j0) {
        const char* src = (const char*)ab + (size_t)j0 * 512;
        #pragma unroll
        for (int i = 0; i < 4; ++i) {
            const int chunk = w * 4 + i;  // 32 chunks x 1 KB = 32 KB tile
            __builtin_amdgcn_global_load_lds(
                (const __attribute__((address_space(1))) void*)
                    (src + chunk * 1024 + lane * 16),
                (__attribute__((address_space(3))) void*)
                    (&lds[buf][chunk * 1024]),
                16, 0, 0);
        }
    };

    float rowsum[2][4] = {{0.f, 0.f, 0.f, 0.f}, {0.f, 0.f, 0.f, 0.f}};
    const int cb = (lane >> 4) * 16;  // byte col base within a k-group
    const int rl = lane & 15;

    stage(0, jstart);

    for (int step = 0; step < nsteps; ++step) {
        __syncthreads();  // drains vmcnt: stage(step) landed; prev reads done
        if (step + 1 < nsteps) stage((step + 1) & 1, jstart + (step + 1) * BN);
        const char* L = lds[step & 1];

        #pragma unroll
        for (int sub = 0; sub < 2; ++sub) {
            const int r0 = rl + sub * 32;
            const int r1 = r0 + 16;

            f32x4 acc[2][2];
            #pragma unroll
            for (int f = 0; f < 2; ++f) {
                acc[f][0] = (f32x4){0.f, 0.f, 0.f, 0.f};
                acc[f][1] = (f32x4){0.f, 0.f, 0.f, 0.f};
            }

            #pragma unroll
            for (int ks = 0; ks < 8; ++ks) {
                const int bcol = ks * 64 + cb;
                bf16x8 b0 = *reinterpret_cast<const bf16x8*>(
                    &L[r0 * 512 + (bcol ^ ((r0 & 7) << 4))]);
                bf16x8 b1 = *reinterpret_cast<const bf16x8*>(
                    &L[r1 * 512 + (bcol ^ ((r1 & 7) << 4))]);
                #pragma unroll
                for (int f = 0; f < 2; ++f) {
                    acc[f][0] = __builtin_amdgcn_mfma_f32_16x16x32_bf16(
                        afrag[f][ks], b0, acc[f][0], 0, 0, 0);
                    acc[f][1] = __builtin_amdgcn_mfma_f32_16x16x32_bf16(
                        afrag[f][ks], b1, acc[f][1], 0, 0, 0);
                }
            }

            // acc[f][g][r] = (2log2e)*s[row=f*16+(lane>>4)*4+r][col group]
            #pragma unroll
            for (int f = 0; f < 2; ++f)
                #pragma unroll
                for (int g = 0; g < 2; ++g)
                    #pragma unroll
                    for (int r = 0; r < 4; ++r)
                        rowsum[f][r] += __builtin_amdgcn_exp2f(acc[f][g][r]);
        }
    }

    // sum across the 16 lanes sharing (lane>>4)
    #pragma unroll
    for (int f = 0; f < 2; ++f)
        #pragma unroll
        for (int r = 0; r < 4; ++r) {
            float s = rowsum[f][r];
            s += __shfl_xor(s, 1);
            s += __shfl_xor(s, 2);
            s += __shfl_xor(s, 4);
            s += __shfl_xor(s, 8);
            rowsum[f][r] = s;
        }

    if ((lane & 15) == 0) {
        const int rbase = mbase + w * 32 + (lane >> 4) * 4;
        #pragma unroll
        for (int f = 0; f < 2; ++f)
            #pragma unroll
            for (int r = 0; r < 4; ++r)
                partial[(size_t)blockIdx.y * MROWS + rbase + f * 16 + r] = rowsum[f][r];
    }
}

__global__ void finalize_kernel(const float* __restrict__ partial,
                                float* __restrict__ out) {
    const int i = blockIdx.x * blockDim.x + threadIdx.x;
    float s = 0.f;
    #pragma unroll
    for (int p = 0; p < NSPLIT; ++p) s += partial[(size_t)p * MROWS + i];
    // energy = -(log(sum)-log M)/2 + 0.5||xn||^2 + 0.5 max||an||^2, norms == 1
    out[i] = -0.5f * (logf(s) - logf((float)NROWS)) + 1.0f;
}

extern "C" void kernel_launch(void* const* d_in, const int* in_sizes, int n_in,
                              void* d_out, int out_size, void* d_ws, size_t ws_size,
                              hipStream_t stream) {
    const float* x = (const float*)d_in[0];
    const float* a = (const float*)d_in[1];
    float* out = (float*)d_out;

    char* ws = (char*)d_ws;
    size_t off = 0;
    __hip_bfloat16* xb = (__hip_bfloat16*)(ws + off); off += (size_t)MROWS * KDIM * 2;  // 4 MiB
    __hip_bfloat16* ab = (__hip_bfloat16*)(ws + off); off += (size_t)NROWS * KDIM * 2;  // 4 MiB
    float* partial     = (float*)(ws + off);          // NSPLIT*MROWS*4 = 512 KiB

    normalize_kernel<<<(2 * MROWS) / 4, 256, 0, stream>>>(x, a, xb, ab);
    expsum_kernel<<<dim3(MROWS / BM, NSPLIT), 512, 0, stream>>>(xb, ab, partial);
    finalize_kernel<<<MROWS / 256, 256, 0, stream>>>(partial, out);
}